// Round 1
// baseline (5064.304 us; speedup 1.0000x reference)
//
#include <hip/hip_runtime.h>
#include <stdint.h>

// ============================================================================
// SliceKernel — exact re-implementation of the JAX threefry slice sampler.
//
// ROUND LADDER (flip on absmax signature):
//   absmax ~1-2        -> PRNG mode wrong: set PRNG_PARTITIONABLE 0
//   absmax ~0.05-0.8   -> sum-order wrong: SUM_MODE 2 -> 1 -> 0 -> 3
//   absmax <= ~1e-3    -> pass / residual ulp noise
// ============================================================================

#define PRNG_PARTITIONABLE 1
#define SUM_MODE 2  // 2=16-lane partials+tree (AVX-512), 1=8-lane (AVX2), 0=sequential f32, 3=f64

#define BD 128   // feature dim D
#define NB 65536 // chains B

// ---------------- threefry2x32 (host + device) ------------------------------
__host__ __device__ inline uint32_t rotl32(uint32_t v, int s) {
  return (v << s) | (v >> (32 - s));
}

__host__ __device__ inline void tf2x32(uint32_t k0, uint32_t k1,
                                       uint32_t c0, uint32_t c1,
                                       uint32_t* o0, uint32_t* o1) {
  uint32_t ks2 = k0 ^ k1 ^ 0x1BD11BDAu;
  uint32_t x0 = c0 + k0, x1 = c1 + k1;
#define TFR(r) x0 += x1; x1 = rotl32(x1, (r)); x1 ^= x0;
  TFR(13) TFR(15) TFR(26) TFR(6)
  x0 += k1;  x1 += ks2 + 1u;
  TFR(17) TFR(29) TFR(16) TFR(24)
  x0 += ks2; x1 += k0 + 2u;
  TFR(13) TFR(15) TFR(26) TFR(6)
  x0 += k0;  x1 += k1 + 3u;
  TFR(17) TFR(29) TFR(16) TFR(24)
  x0 += k1;  x1 += ks2 + 4u;
  TFR(13) TFR(15) TFR(26) TFR(6)
  x0 += ks2; x1 += k0 + 5u;
#undef TFR
  *o0 = x0; *o1 = x1;
}

// jax random_bits (32-bit) for a flat array; n = linear element index.
// Partitionable: fold(threefry(key,(0,n))). Original: split-half pairing, H=N/2.
__device__ inline uint32_t jbits(uint32_t k0, uint32_t k1, uint32_t n, uint32_t H) {
#if PRNG_PARTITIONABLE
  (void)H;
  uint32_t a, b;
  tf2x32(k0, k1, 0u, n, &a, &b);
  return a ^ b;
#else
  uint32_t a, b;
  if (n < H) { tf2x32(k0, k1, n, n + H, &a, &b); return a; }
  else       { tf2x32(k0, k1, n - H, n, &a, &b); return b; }
#endif
}

// ---------------- XLA-exact scalar math -------------------------------------
__device__ inline float u01(uint32_t bits) {
  // bitcast(bits>>9 | 0x3f800000) - 1.0  (exact subtract)
  return __fsub_rn(__uint_as_float((bits >> 9) | 0x3f800000u), 1.0f);
}

// XLA ElementalIrEmitter::EmitLog1p:  |x|<1e-4 ? (−0.5x+1)*x : log(x+1)
// glibc logf is ~correctly rounded; emulate via f64 log then round.
__device__ inline float xla_log1p(float x) {
  float u  = __fadd_rn(x, 1.0f);
  float lg = (float)log((double)u);
  float sm = __fmul_rn(__fadd_rn(__fmul_rn(-0.5f, x), 1.0f), x);
  return (fabsf(x) < 1e-4f) ? sm : lg;
}

// chlo ErfInv32 (Giles), w = -log1p(-x*x), poly p = c + p*w (separate mul/add)
__device__ inline float xla_erfinv(float x) {
  float xx = __fmul_rn(x, x);
  float w  = -xla_log1p(-xx);
  float p;
  if (w < 5.0f) {
    float ww = __fsub_rn(w, 2.5f);
    p = 2.81022636e-08f;
    p = __fadd_rn(3.43273939e-07f,  __fmul_rn(p, ww));
    p = __fadd_rn(-3.5233877e-06f,  __fmul_rn(p, ww));
    p = __fadd_rn(-4.39150654e-06f, __fmul_rn(p, ww));
    p = __fadd_rn(0.00021858087f,   __fmul_rn(p, ww));
    p = __fadd_rn(-0.00125372503f,  __fmul_rn(p, ww));
    p = __fadd_rn(-0.00417768164f,  __fmul_rn(p, ww));
    p = __fadd_rn(0.246640727f,     __fmul_rn(p, ww));
    p = __fadd_rn(1.50140941f,      __fmul_rn(p, ww));
  } else {
    float ww = __fsub_rn(__fsqrt_rn(w), 3.0f);
    p = -0.000200214257f;
    p = __fadd_rn(0.000100950558f,  __fmul_rn(p, ww));
    p = __fadd_rn(0.00134934322f,   __fmul_rn(p, ww));
    p = __fadd_rn(-0.00367342844f,  __fmul_rn(p, ww));
    p = __fadd_rn(0.00573950773f,   __fmul_rn(p, ww));
    p = __fadd_rn(-0.0076224613f,   __fmul_rn(p, ww));
    p = __fadd_rn(0.00943887047f,   __fmul_rn(p, ww));
    p = __fadd_rn(1.00167406f,      __fmul_rn(p, ww));
    p = __fadd_rn(2.83297682f,      __fmul_rn(p, ww));
  }
  return __fmul_rn(p, x);
}

// ---------------- kernel 1: dirs = normalize(normal(k_dir, (B,D))) ----------
__global__ __launch_bounds__(128) void slice_dirs_kernel(float* dirs,
                                                         uint32_t kd0, uint32_t kd1) {
  __shared__ float vsh[BD + 1];
  const int row = blockIdx.x;
  const int t   = threadIdx.x;
  const uint32_t n = ((uint32_t)row << 7) | (uint32_t)t;

  uint32_t bb = jbits(kd0, kd1, n, 4194304u);  // H = B*D/2 (original mode only)
  float f = u01(bb);
  const float LO    = __uint_as_float(0xBF7FFFFFu);  // nextafter(-1,0)
  const float SQRT2 = __uint_as_float(0x3FB504F3u);
  // u = max(lo, f*(hi-lo) + lo); hi-lo rounds to exactly 2.0f
  float um = fmaxf(LO, __fadd_rn(__fmul_rn(f, 2.0f), LO));
  float v  = __fmul_rn(SQRT2, xla_erfinv(um));

  vsh[t] = v;
  __syncthreads();
  if (t == 0) {
    // replicate XLA vectorized-reduce order for sum(d*d) in f32
#if SUM_MODE == 2
    float pr[16];
#pragma unroll
    for (int l = 0; l < 16; ++l) pr[l] = 0.0f;
    for (int m = 0; m < 8; ++m)
#pragma unroll
      for (int l = 0; l < 16; ++l) {
        float vv = vsh[m * 16 + l];
        pr[l] = __fadd_rn(pr[l], __fmul_rn(vv, vv));
      }
    float q0 = __fadd_rn(pr[0], pr[8]),  q1 = __fadd_rn(pr[1], pr[9]);
    float q2 = __fadd_rn(pr[2], pr[10]), q3 = __fadd_rn(pr[3], pr[11]);
    float q4 = __fadd_rn(pr[4], pr[12]), q5 = __fadd_rn(pr[5], pr[13]);
    float q6 = __fadd_rn(pr[6], pr[14]), q7 = __fadd_rn(pr[7], pr[15]);
    float r0 = __fadd_rn(q0, q4), r1 = __fadd_rn(q1, q5);
    float r2 = __fadd_rn(q2, q6), r3 = __fadd_rn(q3, q7);
    float t0 = __fadd_rn(r0, r2), t1 = __fadd_rn(r1, r3);
    float s  = __fadd_rn(t0, t1);
#elif SUM_MODE == 1
    float pr[8];
#pragma unroll
    for (int l = 0; l < 8; ++l) pr[l] = 0.0f;
    for (int m = 0; m < 16; ++m)
#pragma unroll
      for (int l = 0; l < 8; ++l) {
        float vv = vsh[m * 8 + l];
        pr[l] = __fadd_rn(pr[l], __fmul_rn(vv, vv));
      }
    float q0 = __fadd_rn(pr[0], pr[4]), q1 = __fadd_rn(pr[1], pr[5]);
    float q2 = __fadd_rn(pr[2], pr[6]), q3 = __fadd_rn(pr[3], pr[7]);
    float r0 = __fadd_rn(q0, q2), r1 = __fadd_rn(q1, q3);
    float s  = __fadd_rn(r0, r1);
#elif SUM_MODE == 0
    float s = 0.0f;
    for (int m = 0; m < BD; ++m) s = __fadd_rn(s, __fmul_rn(vsh[m], vsh[m]));
#else
    double sd = 0.0;
    for (int m = 0; m < BD; ++m) sd += (double)vsh[m] * (double)vsh[m];
    float s = (float)sd;
#endif
    vsh[BD] = s;
  }
  __syncthreads();
  float nrm = __fsqrt_rn(vsh[BD]);
  dirs[n] = v / nrm;  // IEEE f32 divide (hipcc default: correctly rounded)
}

// ---------------- potential: -0.5 * sum((x+coef*d) @ W.T)^2 -----------------
__device__ __attribute__((always_inline)) inline float potential_body(
    const float* xrow, const float* drow, const float* Wl, float coef) {
  float cand[BD];
#pragma unroll
  for (int k4 = 0; k4 < BD / 4; ++k4) {
    float4 xv = reinterpret_cast<const float4*>(xrow)[k4];
    float4 dv = reinterpret_cast<const float4*>(drow)[k4];
    cand[k4 * 4 + 0] = __fadd_rn(xv.x, __fmul_rn(coef, dv.x));
    cand[k4 * 4 + 1] = __fadd_rn(xv.y, __fmul_rn(coef, dv.y));
    cand[k4 * 4 + 2] = __fadd_rn(xv.z, __fmul_rn(coef, dv.z));
    cand[k4 * 4 + 3] = __fadd_rn(xv.w, __fmul_rn(coef, dv.w));
  }

#if SUM_MODE == 2
  float pr[16];
#pragma unroll
  for (int l = 0; l < 16; ++l) pr[l] = 0.0f;
#elif SUM_MODE == 1
  float pr[8];
#pragma unroll
  for (int l = 0; l < 8; ++l) pr[l] = 0.0f;
#elif SUM_MODE == 0
  float s_acc = 0.0f;
#else
  double s_acc = 0.0;
#endif

#pragma unroll 1
  for (int ib2 = 0; ib2 < 8; ++ib2) {
    // even 8-row half (rows ib2*16 .. +7)
    {
      float z[8] = {0.f, 0.f, 0.f, 0.f, 0.f, 0.f, 0.f, 0.f};
      const float* Wr = &Wl[(ib2 * 16) * BD];
#pragma unroll
      for (int k = 0; k < BD; ++k) {
        float c = cand[k];
#pragma unroll
        for (int j = 0; j < 8; ++j) z[j] = __fmaf_rn(c, Wr[j * BD + k], z[j]);
      }
#pragma unroll
      for (int j = 0; j < 8; ++j) {
        float zz = __fmul_rn(z[j], z[j]);
#if SUM_MODE == 2
        pr[j] = __fadd_rn(pr[j], zz);
#elif SUM_MODE == 1
        pr[j] = __fadd_rn(pr[j], zz);
#elif SUM_MODE == 0
        s_acc = __fadd_rn(s_acc, zz);
#else
        s_acc += (double)zz;
#endif
      }
    }
    // odd 8-row half (rows ib2*16+8 .. +15)
    {
      float z[8] = {0.f, 0.f, 0.f, 0.f, 0.f, 0.f, 0.f, 0.f};
      const float* Wr = &Wl[(ib2 * 16 + 8) * BD];
#pragma unroll
      for (int k = 0; k < BD; ++k) {
        float c = cand[k];
#pragma unroll
        for (int j = 0; j < 8; ++j) z[j] = __fmaf_rn(c, Wr[j * BD + k], z[j]);
      }
#pragma unroll
      for (int j = 0; j < 8; ++j) {
        float zz = __fmul_rn(z[j], z[j]);
#if SUM_MODE == 2
        pr[8 + j] = __fadd_rn(pr[8 + j], zz);
#elif SUM_MODE == 1
        pr[j] = __fadd_rn(pr[j], zz);
#elif SUM_MODE == 0
        s_acc = __fadd_rn(s_acc, zz);
#else
        s_acc += (double)zz;
#endif
      }
    }
  }

#if SUM_MODE == 2
  float q0 = __fadd_rn(pr[0], pr[8]),  q1 = __fadd_rn(pr[1], pr[9]);
  float q2 = __fadd_rn(pr[2], pr[10]), q3 = __fadd_rn(pr[3], pr[11]);
  float q4 = __fadd_rn(pr[4], pr[12]), q5 = __fadd_rn(pr[5], pr[13]);
  float q6 = __fadd_rn(pr[6], pr[14]), q7 = __fadd_rn(pr[7], pr[15]);
  float r0 = __fadd_rn(q0, q4), r1 = __fadd_rn(q1, q5);
  float r2 = __fadd_rn(q2, q6), r3 = __fadd_rn(q3, q7);
  float t0 = __fadd_rn(r0, r2), t1 = __fadd_rn(r1, r3);
  float s  = __fadd_rn(t0, t1);
#elif SUM_MODE == 1
  float q0 = __fadd_rn(pr[0], pr[4]), q1 = __fadd_rn(pr[1], pr[5]);
  float q2 = __fadd_rn(pr[2], pr[6]), q3 = __fadd_rn(pr[3], pr[7]);
  float r0 = __fadd_rn(q0, q2), r1 = __fadd_rn(q1, q3);
  float s  = __fadd_rn(r0, r1);
#elif SUM_MODE == 0
  float s = s_acc;
#else
  float s = (float)s_acc;
#endif
  return __fmul_rn(-0.5f, s);
}

// ---------------- kernel 2: the sampler, one thread per chain ---------------
struct KeyArgs {
  uint32_t ky0, ky1;   // k_y
  uint32_t ku0, ku1;   // k_u0
  uint32_t ks[48];     // 24 shrink keys
};

__global__ __launch_bounds__(256, 1) void slice_main_kernel(
    const float* __restrict__ X, const float* __restrict__ Wg,
    const float* DIRS, float* OUT, KeyArgs ka) {
  __shared__ __align__(16) float Wl[BD * BD];
  for (int i = threadIdx.x; i < BD * BD / 4; i += 256)
    reinterpret_cast<float4*>(Wl)[i] = reinterpret_cast<const float4*>(Wg)[i];
  __syncthreads();

  const int chain = blockIdx.x * 256 + threadIdx.x;
  const float* xrow = X + (size_t)chain * BD;
  const float* drow = DIRS + (size_t)chain * BD;

  // pot0 and y = log1p(-U) + pot0
  float pot0 = potential_body(xrow, drow, Wl, 0.0f);
  float Uy = u01(jbits(ka.ky0, ka.ky1, (uint32_t)chain, 32768u));
  float y  = __fadd_rn(xla_log1p(-Uy), pot0);
  bool mask0 = (y < pot0);

  // bracket expansion: side 0 = lower (sign -1), side 1 = upper (+1)
  float lb = 0.0f, ub = 0.0f;
#pragma unroll 1
  for (int side = 0; side < 2; ++side) {
    bool m = mask0;
    float b = 0.0f, pw = 1.0f;
#pragma unroll 1
    for (int i = 0; i < 16; ++i) {
      if (!__any((int)m)) break;
      float step = __fmul_rn(0.1f, pw);  // 0.1 * 1.5^i, 1.5^i exact for i<=15
      pw = __fmul_rn(pw, 1.5f);
      if (m) {
        b = side ? __fadd_rn(b, step) : __fsub_rn(b, step);
        float pb = potential_body(xrow, drow, Wl, b);
        m = (y < pb);
      }
    }
    if (side == 0) lb = b; else ub = b;
  }

  // initial proposal
  float U0 = u01(jbits(ka.ku0, ka.ku1, (uint32_t)chain, 32768u));
  float u  = __fadd_rn(__fmul_rn(U0, __fsub_rn(ub, lb)), lb);
  float pc = potential_body(xrow, drow, Wl, u);
  bool rej = (pc < y);

  // shrinkage
#pragma unroll 1
  for (int t = 0; t < 24; ++t) {
    if (!__any((int)rej)) break;
    if (rej) {
      if (u < 0.0f) lb = u; else ub = u;
      float Ut = u01(jbits(ka.ks[2 * t], ka.ks[2 * t + 1], (uint32_t)chain, 32768u));
      u = __fadd_rn(__fmul_rn(Ut, __fsub_rn(ub, lb)), lb);
      float pcc = potential_body(xrow, drow, Wl, u);
      rej = (pcc < y);
    }
  }

  // x_new = x + u_final * dirs  (bitwise == reference's selected candidate)
  float* orow = OUT + (size_t)chain * BD;
#pragma unroll
  for (int k4 = 0; k4 < BD / 4; ++k4) {
    float4 xv = reinterpret_cast<const float4*>(xrow)[k4];
    float4 dv = reinterpret_cast<const float4*>(drow)[k4];
    float4 o;
    o.x = __fadd_rn(xv.x, __fmul_rn(u, dv.x));
    o.y = __fadd_rn(xv.y, __fmul_rn(u, dv.y));
    o.z = __fadd_rn(xv.z, __fmul_rn(u, dv.z));
    o.w = __fadd_rn(xv.w, __fmul_rn(u, dv.w));
    reinterpret_cast<float4*>(orow)[k4] = o;
  }
}

// ---------------- launcher ---------------------------------------------------
extern "C" void kernel_launch(void* const* d_in, const int* in_sizes, int n_in,
                              void* d_out, int out_size, void* d_ws, size_t ws_size,
                              hipStream_t stream) {
  (void)in_sizes; (void)n_in; (void)d_ws; (void)ws_size; (void)out_size;
  const float* x = (const float*)d_in[0];
  const float* W = (const float*)d_in[1];
  float* out = (float*)d_out;

  // derive keys host-side (pure integer math, deterministic)
  const uint32_t R0 = 0u, R1 = 42u;  // jax.random.key(42) -> (0, 42)
  uint32_t ky0, ky1, kd0, kd1, ku0, ku1, ksh0, ksh1;
#if PRNG_PARTITIONABLE
  tf2x32(R0, R1, 0u, 0u, &ky0, &ky1);    // split(key,4)[0] = k_y
  tf2x32(R0, R1, 0u, 1u, &kd0, &kd1);    // [1] = k_dir
  tf2x32(R0, R1, 0u, 2u, &ku0, &ku1);    // [2] = k_u0
  tf2x32(R0, R1, 0u, 3u, &ksh0, &ksh1);  // [3] = k_shr
#else
  uint32_t a0, b0, a1, b1, a2, b2, a3, b3;
  tf2x32(R0, R1, 0u, 4u, &a0, &b0);
  tf2x32(R0, R1, 1u, 5u, &a1, &b1);
  tf2x32(R0, R1, 2u, 6u, &a2, &b2);
  tf2x32(R0, R1, 3u, 7u, &a3, &b3);
  ky0 = a0; ky1 = a1; kd0 = a2; kd1 = a3;
  ku0 = b0; ku1 = b1; ksh0 = b2; ksh1 = b3;
#endif

  KeyArgs ka;
  ka.ky0 = ky0; ka.ky1 = ky1; ka.ku0 = ku0; ka.ku1 = ku1;
#if PRNG_PARTITIONABLE
  for (uint32_t t = 0; t < 24; ++t) {
    uint32_t a, b;
    tf2x32(ksh0, ksh1, 0u, t, &a, &b);
    ka.ks[2 * t] = a; ka.ks[2 * t + 1] = b;
  }
#else
  {
    uint32_t f0[24], f1[24];
    for (uint32_t i = 0; i < 24; ++i) tf2x32(ksh0, ksh1, i, i + 24u, &f0[i], &f1[i]);
    uint32_t flat[48];
    for (int i = 0; i < 24; ++i) { flat[i] = f0[i]; flat[24 + i] = f1[i]; }
    for (int i = 0; i < 48; ++i) ka.ks[i] = flat[i];
  }
#endif

  // kernel 1: dirs into d_out (scratch); kernel 2 consumes then overwrites it
  slice_dirs_kernel<<<dim3(NB), dim3(BD), 0, stream>>>(out, kd0, kd1);
  slice_main_kernel<<<dim3(NB / 256), dim3(256), 0, stream>>>(x, W, out, out, ka);
}

// Round 2
// 916.125 us; speedup vs baseline: 5.5280x; 5.5280x over previous
//
#include <hip/hip_runtime.h>
#include <stdint.h>

// ============================================================================
// SliceKernel — exact JAX threefry slice sampler, 16-lanes-per-chain version.
//
// R1 passed (absmax 0.0508): PRNG=partitionable, SUM_MODE=2 (16 partials +
// q/r/t/s tree), Eigen sequential-k FMA dots. DO NOT change any arithmetic
// ordering — only the lane decomposition changed this round:
//   lane l of a 16-lane group owns pr[l] = sum_m zz(row 16m+l)  (m ascending)
//   final combine = XOR butterfly masks 8,4,2,1  == q/r/t/s tree exactly
//   (IEEE fadd is commutative; pairing is preserved).
// ============================================================================

#define BD 128   // feature dim D
#define NB 65536 // chains B
#define WS 132   // padded LDS row stride (floats): banks 4l+4q mod 32 -> 2-way max

// ---------------- threefry2x32 (host + device) ------------------------------
__host__ __device__ inline uint32_t rotl32(uint32_t v, int s) {
  return (v << s) | (v >> (32 - s));
}

__host__ __device__ inline void tf2x32(uint32_t k0, uint32_t k1,
                                       uint32_t c0, uint32_t c1,
                                       uint32_t* o0, uint32_t* o1) {
  uint32_t ks2 = k0 ^ k1 ^ 0x1BD11BDAu;
  uint32_t x0 = c0 + k0, x1 = c1 + k1;
#define TFR(r) x0 += x1; x1 = rotl32(x1, (r)); x1 ^= x0;
  TFR(13) TFR(15) TFR(26) TFR(6)
  x0 += k1;  x1 += ks2 + 1u;
  TFR(17) TFR(29) TFR(16) TFR(24)
  x0 += ks2; x1 += k0 + 2u;
  TFR(13) TFR(15) TFR(26) TFR(6)
  x0 += k0;  x1 += k1 + 3u;
  TFR(17) TFR(29) TFR(16) TFR(24)
  x0 += k1;  x1 += ks2 + 4u;
  TFR(13) TFR(15) TFR(26) TFR(6)
  x0 += ks2; x1 += k0 + 5u;
#undef TFR
  *o0 = x0; *o1 = x1;
}

// jax partitionable random_bits (32-bit): fold(threefry(key,(0,n)))
__device__ inline uint32_t jbits(uint32_t k0, uint32_t k1, uint32_t n) {
  uint32_t a, b;
  tf2x32(k0, k1, 0u, n, &a, &b);
  return a ^ b;
}

// ---------------- XLA-exact scalar math -------------------------------------
__device__ inline float u01(uint32_t bits) {
  return __fsub_rn(__uint_as_float((bits >> 9) | 0x3f800000u), 1.0f);
}

// XLA EmitLog1p: |x|<1e-4 ? (−0.5x+1)*x : log(x+1) (glibc logf ~ f64-log round)
__device__ inline float xla_log1p(float x) {
  float u  = __fadd_rn(x, 1.0f);
  float lg = (float)log((double)u);
  float sm = __fmul_rn(__fadd_rn(__fmul_rn(-0.5f, x), 1.0f), x);
  return (fabsf(x) < 1e-4f) ? sm : lg;
}

// chlo ErfInv32 (Giles), separate mul/add rounding
__device__ inline float xla_erfinv(float x) {
  float xx = __fmul_rn(x, x);
  float w  = -xla_log1p(-xx);
  float p;
  if (w < 5.0f) {
    float ww = __fsub_rn(w, 2.5f);
    p = 2.81022636e-08f;
    p = __fadd_rn(3.43273939e-07f,  __fmul_rn(p, ww));
    p = __fadd_rn(-3.5233877e-06f,  __fmul_rn(p, ww));
    p = __fadd_rn(-4.39150654e-06f, __fmul_rn(p, ww));
    p = __fadd_rn(0.00021858087f,   __fmul_rn(p, ww));
    p = __fadd_rn(-0.00125372503f,  __fmul_rn(p, ww));
    p = __fadd_rn(-0.00417768164f,  __fmul_rn(p, ww));
    p = __fadd_rn(0.246640727f,     __fmul_rn(p, ww));
    p = __fadd_rn(1.50140941f,      __fmul_rn(p, ww));
  } else {
    float ww = __fsub_rn(__fsqrt_rn(w), 3.0f);
    p = -0.000200214257f;
    p = __fadd_rn(0.000100950558f,  __fmul_rn(p, ww));
    p = __fadd_rn(0.00134934322f,   __fmul_rn(p, ww));
    p = __fadd_rn(-0.00367342844f,  __fmul_rn(p, ww));
    p = __fadd_rn(0.00573950773f,   __fmul_rn(p, ww));
    p = __fadd_rn(-0.0076224613f,   __fmul_rn(p, ww));
    p = __fadd_rn(0.00943887047f,   __fmul_rn(p, ww));
    p = __fadd_rn(1.00167406f,      __fmul_rn(p, ww));
    p = __fadd_rn(2.83297682f,      __fmul_rn(p, ww));
  }
  return __fmul_rn(p, x);
}

// ---------------- kernel 1: dirs, one wave per row --------------------------
__global__ __launch_bounds__(1024) void slice_dirs_kernel(float* dirs,
                                                          uint32_t kd0, uint32_t kd1) {
  __shared__ float vsh[16][BD];
  const int tid  = threadIdx.x;
  const int wave = tid >> 6, lane = tid & 63;
  const int row  = blockIdx.x * 16 + wave;
  const int l16  = lane & 15;
  const uint32_t n0 = (uint32_t)row * 128u + (uint32_t)lane;

  const float LO    = __uint_as_float(0xBF7FFFFFu);
  const float SQRT2 = __uint_as_float(0x3FB504F3u);
  float v[2];
#pragma unroll
  for (int h = 0; h < 2; ++h) {
    float f  = u01(jbits(kd0, kd1, n0 + 64u * h));
    float um = fmaxf(LO, __fadd_rn(__fmul_rn(f, 2.0f), LO));
    v[h] = __fmul_rn(SQRT2, xla_erfinv(um));
    vsh[wave][lane + 64 * h] = v[h];
  }
  __syncthreads();  // uniform barrier (all waves, same trip count)

  // pr[l] = sum_{m=0..7} v[16m+l]^2, then q/r/t/s tree via XOR butterfly
  float pr = 0.0f;
#pragma unroll
  for (int m = 0; m < 8; ++m) {
    float vv = vsh[wave][m * 16 + l16];
    pr = __fadd_rn(pr, __fmul_rn(vv, vv));
  }
#pragma unroll
  for (int msk = 8; msk >= 1; msk >>= 1)
    pr = __fadd_rn(pr, __shfl_xor(pr, msk));
  float nrm = __fsqrt_rn(pr);
  dirs[n0]       = v[0] / nrm;
  dirs[n0 + 64u] = v[1] / nrm;
}

// ---------------- 16-lane potential -----------------------------------------
// lane l16 computes rows 16m+l16 (m=0..7), each a sequential-k FMA chain;
// pr accumulation m-ascending; butterfly == reference q/r/t/s tree.
__device__ __attribute__((always_inline)) inline float potential16(
    const float* __restrict__ xr, const float* __restrict__ dr,
    const float* __restrict__ wr, float coef) {
  float z[8] = {0.f, 0.f, 0.f, 0.f, 0.f, 0.f, 0.f, 0.f};
#pragma unroll 2
  for (int q = 0; q < 32; ++q) {
    float4 xv = *(const float4*)(xr + q * 4);
    float4 dv = *(const float4*)(dr + q * 4);
    float c0 = __fadd_rn(xv.x, __fmul_rn(coef, dv.x));
    float c1 = __fadd_rn(xv.y, __fmul_rn(coef, dv.y));
    float c2 = __fadd_rn(xv.z, __fmul_rn(coef, dv.z));
    float c3 = __fadd_rn(xv.w, __fmul_rn(coef, dv.w));
#pragma unroll
    for (int m = 0; m < 8; ++m) {
      float4 wv = *(const float4*)(wr + m * (16 * WS) + q * 4);
      z[m] = __fmaf_rn(c0, wv.x, z[m]);
      z[m] = __fmaf_rn(c1, wv.y, z[m]);
      z[m] = __fmaf_rn(c2, wv.z, z[m]);
      z[m] = __fmaf_rn(c3, wv.w, z[m]);
    }
  }
  float pr = 0.0f;
#pragma unroll
  for (int m = 0; m < 8; ++m) pr = __fadd_rn(pr, __fmul_rn(z[m], z[m]));
#pragma unroll
  for (int msk = 8; msk >= 1; msk >>= 1)
    pr = __fadd_rn(pr, __shfl_xor(pr, msk));
  return __fmul_rn(-0.5f, pr);
}

// ---------------- kernel 2: sampler, 16 lanes per chain ---------------------
struct KeyArgs {
  uint32_t ky0, ky1;   // k_y
  uint32_t ku0, ku1;   // k_u0
  uint32_t ks[48];     // 24 shrink keys
};

__global__ __launch_bounds__(1024, 4) void slice_main_kernel(
    const float* __restrict__ X, const float* __restrict__ Wg,
    const float* __restrict__ DIRS, float* __restrict__ OUT, KeyArgs ka) {
  __shared__ __align__(16) float Wl[128 * WS];  //  67,584 B
  __shared__ __align__(16) float Xl[64 * WS];   //  33,792 B
  __shared__ __align__(16) float Dl[64 * WS];   //  33,792 B  (total 132 KiB)

  const int tid   = threadIdx.x;
  const int cbase = blockIdx.x * 64;

  // stage W (padded rows)
  for (int i = tid; i < 128 * 32; i += 1024) {
    int r = i >> 5, q = i & 31;
    *(float4*)&Wl[r * WS + q * 4] = ((const float4*)Wg)[i];
  }
  // stage x, d rows for this block's 64 chains
  for (int i = tid; i < 64 * 32; i += 1024) {
    int c = i >> 5, q = i & 31;
    *(float4*)&Xl[c * WS + q * 4] = ((const float4*)(X    + (size_t)(cbase + c) * BD))[q];
    *(float4*)&Dl[c * WS + q * 4] = ((const float4*)(DIRS + (size_t)(cbase + c) * BD))[q];
  }
  __syncthreads();  // only block-wide barrier; waves diverge freely afterwards

  const int wave = tid >> 6;
  const int lane = tid & 63;
  const int sub  = lane >> 4;          // chain-subgroup in wave (0..3)
  const int l16  = lane & 15;          // lane-in-chain
  const int cl   = wave * 4 + sub;     // chain local (0..63)
  const uint32_t chain = (uint32_t)(cbase + cl);

  const float* xr = &Xl[cl * WS];
  const float* dr = &Dl[cl * WS];
  const float* wr = &Wl[l16 * WS];     // row 16m+l16 at wr + m*16*WS

  // pot0 and y = log1p(-U) + pot0   (replicated identically across 16 lanes)
  float pot0 = potential16(xr, dr, wr, 0.0f);
  float Uy = u01(jbits(ka.ky0, ka.ky1, chain));
  float y  = __fadd_rn(xla_log1p(-Uy), pot0);
  bool mask0 = (y < pot0);

  // bracket expansion: side 0 = lower (−), side 1 = upper (+)
  float lb = 0.0f, ub = 0.0f;
#pragma unroll 1
  for (int side = 0; side < 2; ++side) {
    bool m = mask0;
    float b = 0.0f, pw = 1.0f;
#pragma unroll 1
    for (int i = 0; i < 16; ++i) {
      if (!__any((int)m)) break;
      float step = __fmul_rn(0.1f, pw);   // 0.1 * 1.5^i (1.5^i exact, i<=15)
      pw = __fmul_rn(pw, 1.5f);
      if (m) {
        b = side ? __fadd_rn(b, step) : __fsub_rn(b, step);
        float pb = potential16(xr, dr, wr, b);
        m = (y < pb);
      }
    }
    if (side == 0) lb = b; else ub = b;
  }

  // initial proposal
  float U0 = u01(jbits(ka.ku0, ka.ku1, chain));
  float u  = __fadd_rn(__fmul_rn(U0, __fsub_rn(ub, lb)), lb);
  float pc = potential16(xr, dr, wr, u);
  bool rej = (pc < y);

  // shrinkage
#pragma unroll 1
  for (int t = 0; t < 24; ++t) {
    if (!__any((int)rej)) break;
    if (rej) {
      if (u < 0.0f) lb = u; else ub = u;
      float Ut = u01(jbits(ka.ks[2 * t], ka.ks[2 * t + 1], chain));
      u = __fadd_rn(__fmul_rn(Ut, __fsub_rn(ub, lb)), lb);
      float pcc = potential16(xr, dr, wr, u);
      rej = (pcc < y);
    }
  }

  // x_new = x + u*dirs — lane l16 writes quads 2*l16, 2*l16+1
  float* orow = OUT + (size_t)chain * BD;
#pragma unroll
  for (int h = 0; h < 2; ++h) {
    int q = l16 * 2 + h;
    float4 xv = *(const float4*)(xr + q * 4);
    float4 dv = *(const float4*)(dr + q * 4);
    float4 o;
    o.x = __fadd_rn(xv.x, __fmul_rn(u, dv.x));
    o.y = __fadd_rn(xv.y, __fmul_rn(u, dv.y));
    o.z = __fadd_rn(xv.z, __fmul_rn(u, dv.z));
    o.w = __fadd_rn(xv.w, __fmul_rn(u, dv.w));
    *(float4*)&orow[q * 4] = o;
  }
}

// ---------------- launcher ---------------------------------------------------
extern "C" void kernel_launch(void* const* d_in, const int* in_sizes, int n_in,
                              void* d_out, int out_size, void* d_ws, size_t ws_size,
                              hipStream_t stream) {
  (void)in_sizes; (void)n_in; (void)d_ws; (void)ws_size; (void)out_size;
  const float* x = (const float*)d_in[0];
  const float* W = (const float*)d_in[1];
  float* out = (float*)d_out;

  // jax.random.key(42) = (0, 42); split(key,4)[i] = threefry(key, (0, i))
  const uint32_t R0 = 0u, R1 = 42u;
  uint32_t ky0, ky1, kd0, kd1, ku0, ku1, ksh0, ksh1;
  tf2x32(R0, R1, 0u, 0u, &ky0, &ky1);
  tf2x32(R0, R1, 0u, 1u, &kd0, &kd1);
  tf2x32(R0, R1, 0u, 2u, &ku0, &ku1);
  tf2x32(R0, R1, 0u, 3u, &ksh0, &ksh1);

  KeyArgs ka;
  ka.ky0 = ky0; ka.ky1 = ky1; ka.ku0 = ku0; ka.ku1 = ku1;
  for (uint32_t t = 0; t < 24; ++t) {
    uint32_t a, b;
    tf2x32(ksh0, ksh1, 0u, t, &a, &b);
    ka.ks[2 * t] = a; ka.ks[2 * t + 1] = b;
  }

  // kernel 1: dirs into d_out (scratch); kernel 2 consumes then overwrites it
  slice_dirs_kernel<<<dim3(NB / 16), dim3(1024), 0, stream>>>(out, kd0, kd1);
  slice_main_kernel<<<dim3(NB / 64), dim3(1024), 0, stream>>>(x, W, out, out, ka);
}

// Round 3
// 192.416 us; speedup vs baseline: 26.3196x; 4.7612x over previous
//
#include <hip/hip_runtime.h>
#include <stdint.h>
#include <math.h>

// ============================================================================
// SliceKernel — exact JAX threefry slice sampler.
// R3 architecture: per chain, compute a = Wx (== exact z at coef=0 -> exact
// pot0) and b = Wd once via the bit-exact 16-lane chain matvec; then run the
// whole bracket/shrink sampler on the f64 quadratic ps(u) = pot0 - u g - u²h/2
// (g = a·b, h = ‖b‖²). Comparisons fall back to the bit-exact chain potential
// only when |ps - y| <= eps(u). All value-producing arithmetic (b-schedule,
// u updates, final x+u·d) is IDENTICAL to R1/R2 (which passed, absmax 0.0508).
//   lane l16 owns W rows 16m+l16 (m=0..7); SUM_MODE2 = 16 partials m-ascending
//   + q/r/t/s tree == XOR butterfly masks 8,4,2,1.
// ============================================================================

#define BD 128   // feature dim D
#define NB 65536 // chains B
#define WS 132   // padded LDS row stride (floats)

// ---------------- threefry2x32 (host + device) ------------------------------
__host__ __device__ inline uint32_t rotl32(uint32_t v, int s) {
  return (v << s) | (v >> (32 - s));
}

__host__ __device__ inline void tf2x32(uint32_t k0, uint32_t k1,
                                       uint32_t c0, uint32_t c1,
                                       uint32_t* o0, uint32_t* o1) {
  uint32_t ks2 = k0 ^ k1 ^ 0x1BD11BDAu;
  uint32_t x0 = c0 + k0, x1 = c1 + k1;
#define TFR(r) x0 += x1; x1 = rotl32(x1, (r)); x1 ^= x0;
  TFR(13) TFR(15) TFR(26) TFR(6)
  x0 += k1;  x1 += ks2 + 1u;
  TFR(17) TFR(29) TFR(16) TFR(24)
  x0 += ks2; x1 += k0 + 2u;
  TFR(13) TFR(15) TFR(26) TFR(6)
  x0 += k0;  x1 += k1 + 3u;
  TFR(17) TFR(29) TFR(16) TFR(24)
  x0 += k1;  x1 += ks2 + 4u;
  TFR(13) TFR(15) TFR(26) TFR(6)
  x0 += ks2; x1 += k0 + 5u;
#undef TFR
  *o0 = x0; *o1 = x1;
}

// jax partitionable random_bits (32-bit): fold(threefry(key,(0,n)))
__device__ inline uint32_t jbits(uint32_t k0, uint32_t k1, uint32_t n) {
  uint32_t a, b;
  tf2x32(k0, k1, 0u, n, &a, &b);
  return a ^ b;
}

// ---------------- XLA-exact scalar math -------------------------------------
__device__ inline float u01(uint32_t bits) {
  return __fsub_rn(__uint_as_float((bits >> 9) | 0x3f800000u), 1.0f);
}

__device__ inline float xla_log1p(float x) {
  float u  = __fadd_rn(x, 1.0f);
  float lg = (float)log((double)u);
  float sm = __fmul_rn(__fadd_rn(__fmul_rn(-0.5f, x), 1.0f), x);
  return (fabsf(x) < 1e-4f) ? sm : lg;
}

__device__ inline float xla_erfinv(float x) {
  float xx = __fmul_rn(x, x);
  float w  = -xla_log1p(-xx);
  float p;
  if (w < 5.0f) {
    float ww = __fsub_rn(w, 2.5f);
    p = 2.81022636e-08f;
    p = __fadd_rn(3.43273939e-07f,  __fmul_rn(p, ww));
    p = __fadd_rn(-3.5233877e-06f,  __fmul_rn(p, ww));
    p = __fadd_rn(-4.39150654e-06f, __fmul_rn(p, ww));
    p = __fadd_rn(0.00021858087f,   __fmul_rn(p, ww));
    p = __fadd_rn(-0.00125372503f,  __fmul_rn(p, ww));
    p = __fadd_rn(-0.00417768164f,  __fmul_rn(p, ww));
    p = __fadd_rn(0.246640727f,     __fmul_rn(p, ww));
    p = __fadd_rn(1.50140941f,      __fmul_rn(p, ww));
  } else {
    float ww = __fsub_rn(__fsqrt_rn(w), 3.0f);
    p = -0.000200214257f;
    p = __fadd_rn(0.000100950558f,  __fmul_rn(p, ww));
    p = __fadd_rn(0.00134934322f,   __fmul_rn(p, ww));
    p = __fadd_rn(-0.00367342844f,  __fmul_rn(p, ww));
    p = __fadd_rn(0.00573950773f,   __fmul_rn(p, ww));
    p = __fadd_rn(-0.0076224613f,   __fmul_rn(p, ww));
    p = __fadd_rn(0.00943887047f,   __fmul_rn(p, ww));
    p = __fadd_rn(1.00167406f,      __fmul_rn(p, ww));
    p = __fadd_rn(2.83297682f,      __fmul_rn(p, ww));
  }
  return __fmul_rn(p, x);
}

// ---------------- kernel 1: dirs, one wave per row --------------------------
__global__ __launch_bounds__(1024) void slice_dirs_kernel(float* dirs,
                                                          uint32_t kd0, uint32_t kd1) {
  __shared__ float vsh[16][BD];
  const int tid  = threadIdx.x;
  const int wave = tid >> 6, lane = tid & 63;
  const int row  = blockIdx.x * 16 + wave;
  const int l16  = lane & 15;
  const uint32_t n0 = (uint32_t)row * 128u + (uint32_t)lane;

  const float LO    = __uint_as_float(0xBF7FFFFFu);
  const float SQRT2 = __uint_as_float(0x3FB504F3u);
  float v[2];
#pragma unroll
  for (int h = 0; h < 2; ++h) {
    float f  = u01(jbits(kd0, kd1, n0 + 64u * h));
    float um = fmaxf(LO, __fadd_rn(__fmul_rn(f, 2.0f), LO));
    v[h] = __fmul_rn(SQRT2, xla_erfinv(um));
    vsh[wave][lane + 64 * h] = v[h];
  }
  __syncthreads();

  float pr = 0.0f;
#pragma unroll
  for (int m = 0; m < 8; ++m) {
    float vv = vsh[wave][m * 16 + l16];
    pr = __fadd_rn(pr, __fmul_rn(vv, vv));
  }
#pragma unroll
  for (int msk = 8; msk >= 1; msk >>= 1)
    pr = __fadd_rn(pr, __shfl_xor(pr, msk));
  float nrm = __fsqrt_rn(pr);
  dirs[n0]       = v[0] / nrm;
  dirs[n0 + 64u] = v[1] / nrm;
}

// ---------------- bit-exact 16-lane chain matvec / potential ----------------
// lane l16 computes rows 16m+l16 (m=0..7), sequential-k FMA chain each.
__device__ __attribute__((always_inline)) inline void matvec16(
    const float* __restrict__ sr, const float* __restrict__ wr, float z[8]) {
#pragma unroll
  for (int m = 0; m < 8; ++m) z[m] = 0.0f;
#pragma unroll 2
  for (int q = 0; q < 32; ++q) {
    float4 cv = *(const float4*)(sr + q * 4);
#pragma unroll
    for (int m = 0; m < 8; ++m) {
      float4 wv = *(const float4*)(wr + m * (16 * WS) + q * 4);
      z[m] = __fmaf_rn(cv.x, wv.x, z[m]);
      z[m] = __fmaf_rn(cv.y, wv.y, z[m]);
      z[m] = __fmaf_rn(cv.z, wv.z, z[m]);
      z[m] = __fmaf_rn(cv.w, wv.w, z[m]);
    }
  }
}

__device__ __attribute__((always_inline)) inline float reduce_pot(const float z[8]) {
  float pr = 0.0f;
#pragma unroll
  for (int m = 0; m < 8; ++m) pr = __fadd_rn(pr, __fmul_rn(z[m], z[m]));
#pragma unroll
  for (int msk = 8; msk >= 1; msk >>= 1)
    pr = __fadd_rn(pr, __shfl_xor(pr, msk));
  return __fmul_rn(-0.5f, pr);
}

// full bit-exact potential at cand = x + coef*d (the fallback path)
__device__ __attribute__((always_inline)) inline float potential16(
    const float* __restrict__ xr, const float* __restrict__ dr,
    const float* __restrict__ wr, float coef) {
  float z[8] = {0.f, 0.f, 0.f, 0.f, 0.f, 0.f, 0.f, 0.f};
#pragma unroll 2
  for (int q = 0; q < 32; ++q) {
    float4 xv = *(const float4*)(xr + q * 4);
    float4 dv = *(const float4*)(dr + q * 4);
    float c0 = __fadd_rn(xv.x, __fmul_rn(coef, dv.x));
    float c1 = __fadd_rn(xv.y, __fmul_rn(coef, dv.y));
    float c2 = __fadd_rn(xv.z, __fmul_rn(coef, dv.z));
    float c3 = __fadd_rn(xv.w, __fmul_rn(coef, dv.w));
#pragma unroll
    for (int m = 0; m < 8; ++m) {
      float4 wv = *(const float4*)(wr + m * (16 * WS) + q * 4);
      z[m] = __fmaf_rn(c0, wv.x, z[m]);
      z[m] = __fmaf_rn(c1, wv.y, z[m]);
      z[m] = __fmaf_rn(c2, wv.z, z[m]);
      z[m] = __fmaf_rn(c3, wv.w, z[m]);
    }
  }
  return reduce_pot(z);
}

// certainty margin for the quadratic prediction (≈30σ over worst chain error)
__device__ inline double epsb(float u) {
  double au = fabs((double)u);
  return 1.5e-3 + 2e-4 * au + 2e-5 * au * au;
}

// ---------------- kernel 2: sampler, 16 lanes per chain ---------------------
struct KeyArgs {
  uint32_t ky0, ky1;   // k_y
  uint32_t ku0, ku1;   // k_u0
  uint32_t ks[48];     // 24 shrink keys
};

__global__ __launch_bounds__(1024, 4) void slice_main_kernel(
    const float* __restrict__ X, const float* __restrict__ Wg,
    const float* __restrict__ DIRS, float* __restrict__ OUT, KeyArgs ka) {
  __shared__ __align__(16) float Wl[128 * WS];
  __shared__ __align__(16) float Xl[64 * WS];
  __shared__ __align__(16) float Dl[64 * WS];

  const int tid   = threadIdx.x;
  const int cbase = blockIdx.x * 64;

  for (int i = tid; i < 128 * 32; i += 1024) {
    int r = i >> 5, q = i & 31;
    *(float4*)&Wl[r * WS + q * 4] = ((const float4*)Wg)[i];
  }
  for (int i = tid; i < 64 * 32; i += 1024) {
    int c = i >> 5, q = i & 31;
    *(float4*)&Xl[c * WS + q * 4] = ((const float4*)(X    + (size_t)(cbase + c) * BD))[q];
    *(float4*)&Dl[c * WS + q * 4] = ((const float4*)(DIRS + (size_t)(cbase + c) * BD))[q];
  }
  __syncthreads();

  const int wave = tid >> 6;
  const int lane = tid & 63;
  const int sub  = lane >> 4;
  const int l16  = lane & 15;
  const int cl   = wave * 4 + sub;
  const uint32_t chain = (uint32_t)(cbase + cl);

  const float* xr = &Xl[cl * WS];
  const float* dr = &Dl[cl * WS];
  const float* wr = &Wl[l16 * WS];

  // ---- exact a = Wx (-> exact pot0), exact-path b = Wd ----
  float av[8], bv[8];
  matvec16(xr, wr, av);          // cand == x bitwise (coef=0 path)
  float pot0 = reduce_pot(av);
  matvec16(dr, wr, bv);

  // quadratic coefficients (prediction only; order-free, f64)
  double gl = 0.0, hl = 0.0;
#pragma unroll
  for (int m = 0; m < 8; ++m) {
    gl += (double)av[m] * (double)bv[m];
    hl += (double)bv[m] * (double)bv[m];
  }
#pragma unroll
  for (int msk = 8; msk >= 1; msk >>= 1) {
    gl += __shfl_xor(gl, msk);
    hl += __shfl_xor(hl, msk);
  }
  const double g = gl, h = hl;
  const double potd0 = (double)pot0;

  // ---- y = log1p(-U) + pot0 (exact f32) ----
  float Uy = u01(jbits(ka.ky0, ka.ky1, chain));
  float y  = __fadd_rn(xla_log1p(-Uy), pot0);
  const double yd = (double)y;
  bool mask0 = (y < pot0);

  // ---- bracket expansion: side 0 = lower (−), side 1 = upper (+) ----
  float lb = 0.0f, ub = 0.0f;
#pragma unroll 1
  for (int side = 0; side < 2; ++side) {
    bool m = mask0;
    float b = 0.0f, pw = 1.0f;
#pragma unroll 1
    for (int i = 0; i < 16; ++i) {
      if (!__any((int)m)) break;
      float step = __fmul_rn(0.1f, pw);
      pw = __fmul_rn(pw, 1.5f);
      if (m) b = side ? __fadd_rn(b, step) : __fsub_rn(b, step);
      // decision: y < pot(b) ?
      double bd   = (double)b;
      double diff = (potd0 - bd * g - 0.5 * bd * bd * h) - yd;
      bool need = m && (fabs(diff) <= epsb(b));
      float pe = 0.0f;
      if (__any((int)need)) pe = potential16(xr, dr, wr, b);  // wave-uniform branch
      bool cont = need ? (y < pe) : (diff > 0.0);
      m = m && cont;
    }
    if (side == 0) lb = b; else ub = b;
  }

  // ---- initial proposal ----
  float U0 = u01(jbits(ka.ku0, ka.ku1, chain));
  float u  = __fadd_rn(__fmul_rn(U0, __fsub_rn(ub, lb)), lb);
  bool rej;
  {
    double ud   = (double)u;
    double diff = (potd0 - ud * g - 0.5 * ud * ud * h) - yd;
    bool need = fabs(diff) <= epsb(u);
    float pe = 0.0f;
    if (__any((int)need)) pe = potential16(xr, dr, wr, u);
    rej = need ? (pe < y) : (diff < 0.0);
  }

  // ---- shrinkage ----
#pragma unroll 1
  for (int t = 0; t < 24; ++t) {
    if (!__any((int)rej)) break;
    if (rej) {
      if (u < 0.0f) lb = u; else ub = u;
      float Ut = u01(jbits(ka.ks[2 * t], ka.ks[2 * t + 1], chain));
      u = __fadd_rn(__fmul_rn(Ut, __fsub_rn(ub, lb)), lb);
    }
    double ud   = (double)u;
    double diff = (potd0 - ud * g - 0.5 * ud * ud * h) - yd;
    bool need = rej && (fabs(diff) <= epsb(u));
    float pe = 0.0f;
    if (__any((int)need)) pe = potential16(xr, dr, wr, u);
    bool rj = need ? (pe < y) : (diff < 0.0);
    rej = rej && rj;
  }

  // ---- x_new = x + u*dirs (exact) ----
  float* orow = OUT + (size_t)chain * BD;
#pragma unroll
  for (int hh = 0; hh < 2; ++hh) {
    int q = l16 * 2 + hh;
    float4 xv = *(const float4*)(xr + q * 4);
    float4 dv = *(const float4*)(dr + q * 4);
    float4 o;
    o.x = __fadd_rn(xv.x, __fmul_rn(u, dv.x));
    o.y = __fadd_rn(xv.y, __fmul_rn(u, dv.y));
    o.z = __fadd_rn(xv.z, __fmul_rn(u, dv.z));
    o.w = __fadd_rn(xv.w, __fmul_rn(u, dv.w));
    *(float4*)&orow[q * 4] = o;
  }
}

// ---------------- launcher ---------------------------------------------------
extern "C" void kernel_launch(void* const* d_in, const int* in_sizes, int n_in,
                              void* d_out, int out_size, void* d_ws, size_t ws_size,
                              hipStream_t stream) {
  (void)in_sizes; (void)n_in; (void)d_ws; (void)ws_size; (void)out_size;
  const float* x = (const float*)d_in[0];
  const float* W = (const float*)d_in[1];
  float* out = (float*)d_out;

  const uint32_t R0 = 0u, R1 = 42u;  // jax.random.key(42)
  uint32_t ky0, ky1, kd0, kd1, ku0, ku1, ksh0, ksh1;
  tf2x32(R0, R1, 0u, 0u, &ky0, &ky1);
  tf2x32(R0, R1, 0u, 1u, &kd0, &kd1);
  tf2x32(R0, R1, 0u, 2u, &ku0, &ku1);
  tf2x32(R0, R1, 0u, 3u, &ksh0, &ksh1);

  KeyArgs ka;
  ka.ky0 = ky0; ka.ky1 = ky1; ka.ku0 = ku0; ka.ku1 = ku1;
  for (uint32_t t = 0; t < 24; ++t) {
    uint32_t a, b;
    tf2x32(ksh0, ksh1, 0u, t, &a, &b);
    ka.ks[2 * t] = a; ka.ks[2 * t + 1] = b;
  }

  slice_dirs_kernel<<<dim3(NB / 16), dim3(1024), 0, stream>>>(out, kd0, kd1);
  slice_main_kernel<<<dim3(NB / 64), dim3(1024), 0, stream>>>(x, W, out, out, ka);
}

// Round 4
// 156.975 us; speedup vs baseline: 32.2618x; 1.2258x over previous
//
#include <hip/hip_runtime.h>
#include <stdint.h>
#include <math.h>

// ============================================================================
// SliceKernel — exact JAX threefry slice sampler, single fused kernel.
// R4: (1) fused av/bv matvec (one W pass), (2) lane remap chain=lane&3,
// j=lane>>2 so W reads are 4-way broadcast / x,d reads 16-way broadcast,
// (3) dirs generation fused in (no DIRS global traffic, no 2nd kernel).
// VALUE-PATH ARITHMETIC IS FROZEN (passed R1-R3, absmax 0.05078125):
//   - dirs: u01 -> um -> sqrt2*erfinv -> /nrm ; norm = partial[j] m-ascending
//     then tree pairing j^8, j^4, j^2, j^1  (= shfl_xor 32,16,8,4 here)
//   - pot: per-row k-ascending FMA chain; partials m-ascending; same tree
//   - sampler: b-schedule, u updates, x+u*d exactly as reference
// Decisions use the f64 quadratic ps(u)=pot0-u g-u^2 h/2 with eps guard;
// near-ties fall back to the bit-exact chain potential (proven R3: 0 flips).
// ============================================================================

#define BD 128   // feature dim D
#define NB 65536 // chains B
#define WS 132   // padded LDS row stride (floats)

// ---------------- threefry2x32 (host + device) ------------------------------
__host__ __device__ inline uint32_t rotl32(uint32_t v, int s) {
  return (v << s) | (v >> (32 - s));
}

__host__ __device__ inline void tf2x32(uint32_t k0, uint32_t k1,
                                       uint32_t c0, uint32_t c1,
                                       uint32_t* o0, uint32_t* o1) {
  uint32_t ks2 = k0 ^ k1 ^ 0x1BD11BDAu;
  uint32_t x0 = c0 + k0, x1 = c1 + k1;
#define TFR(r) x0 += x1; x1 = rotl32(x1, (r)); x1 ^= x0;
  TFR(13) TFR(15) TFR(26) TFR(6)
  x0 += k1;  x1 += ks2 + 1u;
  TFR(17) TFR(29) TFR(16) TFR(24)
  x0 += ks2; x1 += k0 + 2u;
  TFR(13) TFR(15) TFR(26) TFR(6)
  x0 += k0;  x1 += k1 + 3u;
  TFR(17) TFR(29) TFR(16) TFR(24)
  x0 += k1;  x1 += ks2 + 4u;
  TFR(13) TFR(15) TFR(26) TFR(6)
  x0 += ks2; x1 += k0 + 5u;
#undef TFR
  *o0 = x0; *o1 = x1;
}

__device__ inline uint32_t jbits(uint32_t k0, uint32_t k1, uint32_t n) {
  uint32_t a, b;
  tf2x32(k0, k1, 0u, n, &a, &b);
  return a ^ b;
}

// ---------------- XLA-exact scalar math -------------------------------------
__device__ inline float u01(uint32_t bits) {
  return __fsub_rn(__uint_as_float((bits >> 9) | 0x3f800000u), 1.0f);
}

__device__ inline float xla_log1p(float x) {
  float u  = __fadd_rn(x, 1.0f);
  float lg = (float)log((double)u);
  float sm = __fmul_rn(__fadd_rn(__fmul_rn(-0.5f, x), 1.0f), x);
  return (fabsf(x) < 1e-4f) ? sm : lg;
}

__device__ inline float xla_erfinv(float x) {
  float xx = __fmul_rn(x, x);
  float w  = -xla_log1p(-xx);
  float p;
  if (w < 5.0f) {
    float ww = __fsub_rn(w, 2.5f);
    p = 2.81022636e-08f;
    p = __fadd_rn(3.43273939e-07f,  __fmul_rn(p, ww));
    p = __fadd_rn(-3.5233877e-06f,  __fmul_rn(p, ww));
    p = __fadd_rn(-4.39150654e-06f, __fmul_rn(p, ww));
    p = __fadd_rn(0.00021858087f,   __fmul_rn(p, ww));
    p = __fadd_rn(-0.00125372503f,  __fmul_rn(p, ww));
    p = __fadd_rn(-0.00417768164f,  __fmul_rn(p, ww));
    p = __fadd_rn(0.246640727f,     __fmul_rn(p, ww));
    p = __fadd_rn(1.50140941f,      __fmul_rn(p, ww));
  } else {
    float ww = __fsub_rn(__fsqrt_rn(w), 3.0f);
    p = -0.000200214257f;
    p = __fadd_rn(0.000100950558f,  __fmul_rn(p, ww));
    p = __fadd_rn(0.00134934322f,   __fmul_rn(p, ww));
    p = __fadd_rn(-0.00367342844f,  __fmul_rn(p, ww));
    p = __fadd_rn(0.00573950773f,   __fmul_rn(p, ww));
    p = __fadd_rn(-0.0076224613f,   __fmul_rn(p, ww));
    p = __fadd_rn(0.00943887047f,   __fmul_rn(p, ww));
    p = __fadd_rn(1.00167406f,      __fmul_rn(p, ww));
    p = __fadd_rn(2.83297682f,      __fmul_rn(p, ww));
  }
  return __fmul_rn(p, x);
}

// ---------------- bit-exact chain potential (fallback path) -----------------
// lane owns rows 16m+j (m=0..7); k-ascending FMA chain; partials m-ascending;
// tree = shfl_xor 32,16,8,4 (pairs partial-index bits 3,2,1,0 like SUM_MODE2).
__device__ __attribute__((always_inline)) inline float potential16(
    const float* __restrict__ xr, const float* __restrict__ dr,
    const float* __restrict__ wr, float coef) {
  float z[8] = {0.f, 0.f, 0.f, 0.f, 0.f, 0.f, 0.f, 0.f};
#pragma unroll 2
  for (int q = 0; q < 32; ++q) {
    float4 xv = *(const float4*)(xr + q * 4);
    float4 dv = *(const float4*)(dr + q * 4);
    float c0 = __fadd_rn(xv.x, __fmul_rn(coef, dv.x));
    float c1 = __fadd_rn(xv.y, __fmul_rn(coef, dv.y));
    float c2 = __fadd_rn(xv.z, __fmul_rn(coef, dv.z));
    float c3 = __fadd_rn(xv.w, __fmul_rn(coef, dv.w));
#pragma unroll
    for (int m = 0; m < 8; ++m) {
      float4 wv = *(const float4*)(wr + m * (16 * WS) + q * 4);
      z[m] = __fmaf_rn(c0, wv.x, z[m]);
      z[m] = __fmaf_rn(c1, wv.y, z[m]);
      z[m] = __fmaf_rn(c2, wv.z, z[m]);
      z[m] = __fmaf_rn(c3, wv.w, z[m]);
    }
  }
  float pr = 0.0f;
#pragma unroll
  for (int m = 0; m < 8; ++m) pr = __fadd_rn(pr, __fmul_rn(z[m], z[m]));
#pragma unroll
  for (int msk = 32; msk >= 4; msk >>= 1)
    pr = __fadd_rn(pr, __shfl_xor(pr, msk));
  return __fmul_rn(-0.5f, pr);
}

// certainty margin for the quadratic prediction
__device__ inline double epsb(float u) {
  double au = fabs((double)u);
  return 1.5e-3 + 2e-4 * au + 2e-5 * au * au;
}

// ---------------- the single fused kernel -----------------------------------
struct KeyArgs {
  uint32_t ky0, ky1;   // k_y
  uint32_t ku0, ku1;   // k_u0
  uint32_t kd0, kd1;   // k_dir
  uint32_t ks[48];     // 24 shrink keys
};

__global__ __launch_bounds__(1024, 1) void slice_fused_kernel(
    const float* __restrict__ X, const float* __restrict__ Wg,
    float* __restrict__ OUT, KeyArgs ka) {
  __shared__ __align__(16) float Wl[128 * WS];  // 67,584 B
  __shared__ __align__(16) float Xl[64 * WS];   // 33,792 B
  __shared__ __align__(16) float Dl[64 * WS];   // 33,792 B

  const int tid   = threadIdx.x;
  const int cbase = blockIdx.x * 64;

  // ---- stage W, X (async-ish: issue before dirs compute) ----
  for (int i = tid; i < 128 * 32; i += 1024) {
    int r = i >> 5, q = i & 31;
    *(float4*)&Wl[r * WS + q * 4] = ((const float4*)Wg)[i];
  }
  for (int i = tid; i < 64 * 32; i += 1024) {
    int c = i >> 5, q = i & 31;
    *(float4*)&Xl[c * WS + q * 4] = ((const float4*)(X + (size_t)(cbase + c) * BD))[q];
  }

  const int wave = tid >> 6, lane = tid & 63;
  const int c    = lane & 3;          // chain-in-wave
  const int j    = lane >> 2;         // partial index 0..15 (rows 16m+j)
  const int cl   = wave * 4 + c;      // chain local (0..63)
  const uint32_t chain = (uint32_t)(cbase + cl);

  // ---- dirs phase (registers only; overlaps staging latency) ----
  {
    const float LO    = __uint_as_float(0xBF7FFFFFu);
    const float SQRT2 = __uint_as_float(0x3FB504F3u);
    float vm[8];
#pragma unroll
    for (int m = 0; m < 8; ++m) {
      uint32_t n = chain * 128u + (uint32_t)(16 * m + j);
      float f  = u01(jbits(ka.kd0, ka.kd1, n));
      float um = fmaxf(LO, __fadd_rn(__fmul_rn(f, 2.0f), LO));
      vm[m] = __fmul_rn(SQRT2, xla_erfinv(um));
    }
    float pr = 0.0f;
#pragma unroll
    for (int m = 0; m < 8; ++m) pr = __fadd_rn(pr, __fmul_rn(vm[m], vm[m]));
#pragma unroll
    for (int msk = 32; msk >= 4; msk >>= 1)
      pr = __fadd_rn(pr, __shfl_xor(pr, msk));
    float nrm = __fsqrt_rn(pr);
#pragma unroll
    for (int m = 0; m < 8; ++m)
      Dl[cl * WS + 16 * m + j] = vm[m] / nrm;
  }

  __syncthreads();  // single block barrier: staging + Dl complete

  const float* xr = &Xl[cl * WS];
  const float* dr = &Dl[cl * WS];
  const float* wr = &Wl[j * WS];      // row 16m+j at wr + m*16*WS

  // ---- fused matvec: za = W x (chain-exact), zb = W d (surrogate only) ----
  float za[8], zb[8];
#pragma unroll
  for (int m = 0; m < 8; ++m) { za[m] = 0.0f; zb[m] = 0.0f; }
#pragma unroll 2
  for (int q = 0; q < 32; ++q) {
    float4 xv = *(const float4*)(xr + q * 4);
    float4 dv = *(const float4*)(dr + q * 4);
#pragma unroll
    for (int m = 0; m < 8; ++m) {
      float4 wv = *(const float4*)(wr + m * (16 * WS) + q * 4);
      za[m] = __fmaf_rn(xv.x, wv.x, za[m]);
      za[m] = __fmaf_rn(xv.y, wv.y, za[m]);
      za[m] = __fmaf_rn(xv.z, wv.z, za[m]);
      za[m] = __fmaf_rn(xv.w, wv.w, za[m]);
      zb[m] = __fmaf_rn(dv.x, wv.x, zb[m]);
      zb[m] = __fmaf_rn(dv.y, wv.y, zb[m]);
      zb[m] = __fmaf_rn(dv.z, wv.z, zb[m]);
      zb[m] = __fmaf_rn(dv.w, wv.w, zb[m]);
    }
  }

  // pot0: chain-exact f32 reduce (partials m-ascending + tree)
  float pr0 = 0.0f;
#pragma unroll
  for (int m = 0; m < 8; ++m) pr0 = __fadd_rn(pr0, __fmul_rn(za[m], za[m]));
#pragma unroll
  for (int msk = 32; msk >= 4; msk >>= 1)
    pr0 = __fadd_rn(pr0, __shfl_xor(pr0, msk));
  float pot0 = __fmul_rn(-0.5f, pr0);

  // g = a·b, h = ‖b‖² in f64 (surrogate only; order-free)
  double gl = 0.0, hl = 0.0;
#pragma unroll
  for (int m = 0; m < 8; ++m) {
    gl += (double)za[m] * (double)zb[m];
    hl += (double)zb[m] * (double)zb[m];
  }
#pragma unroll
  for (int msk = 32; msk >= 4; msk >>= 1) {
    gl += __shfl_xor(gl, msk);
    hl += __shfl_xor(hl, msk);
  }
  const double g = gl, h = hl;
  const double potd0 = (double)pot0;

  // ---- y = log1p(-U) + pot0 (exact f32) ----
  float Uy = u01(jbits(ka.ky0, ka.ky1, chain));
  float y  = __fadd_rn(xla_log1p(-Uy), pot0);
  const double yd = (double)y;
  bool mask0 = (y < pot0);

  // ---- bracket expansion ----
  float lb = 0.0f, ub = 0.0f;
#pragma unroll 1
  for (int side = 0; side < 2; ++side) {
    bool m = mask0;
    float b = 0.0f, pw = 1.0f;
#pragma unroll 1
    for (int i = 0; i < 16; ++i) {
      if (!__any((int)m)) break;
      float step = __fmul_rn(0.1f, pw);
      pw = __fmul_rn(pw, 1.5f);
      if (m) b = side ? __fadd_rn(b, step) : __fsub_rn(b, step);
      double bd   = (double)b;
      double diff = (potd0 - bd * g - 0.5 * bd * bd * h) - yd;
      bool need = m && (fabs(diff) <= epsb(b));
      float pe = 0.0f;
      if (__any((int)need)) pe = potential16(xr, dr, wr, b);
      bool cont = need ? (y < pe) : (diff > 0.0);
      m = m && cont;
    }
    if (side == 0) lb = b; else ub = b;
  }

  // ---- initial proposal ----
  float U0 = u01(jbits(ka.ku0, ka.ku1, chain));
  float u  = __fadd_rn(__fmul_rn(U0, __fsub_rn(ub, lb)), lb);
  bool rej;
  {
    double ud   = (double)u;
    double diff = (potd0 - ud * g - 0.5 * ud * ud * h) - yd;
    bool need = fabs(diff) <= epsb(u);
    float pe = 0.0f;
    if (__any((int)need)) pe = potential16(xr, dr, wr, u);
    rej = need ? (pe < y) : (diff < 0.0);
  }

  // ---- shrinkage ----
#pragma unroll 1
  for (int t = 0; t < 24; ++t) {
    if (!__any((int)rej)) break;
    if (rej) {
      if (u < 0.0f) lb = u; else ub = u;
      float Ut = u01(jbits(ka.ks[2 * t], ka.ks[2 * t + 1], chain));
      u = __fadd_rn(__fmul_rn(Ut, __fsub_rn(ub, lb)), lb);
    }
    double ud   = (double)u;
    double diff = (potd0 - ud * g - 0.5 * ud * ud * h) - yd;
    bool need = rej && (fabs(diff) <= epsb(u));
    float pe = 0.0f;
    if (__any((int)need)) pe = potential16(xr, dr, wr, u);
    bool rj = need ? (pe < y) : (diff < 0.0);
    rej = rej && rj;
  }

  // ---- x_new = x + u*dirs (exact); lane (c,j) writes quads 2j, 2j+1 ----
  float* orow = OUT + (size_t)chain * BD;
#pragma unroll
  for (int hh = 0; hh < 2; ++hh) {
    int q = j * 2 + hh;
    float4 xv = *(const float4*)(xr + q * 4);
    float4 dv = *(const float4*)(dr + q * 4);
    float4 o;
    o.x = __fadd_rn(xv.x, __fmul_rn(u, dv.x));
    o.y = __fadd_rn(xv.y, __fmul_rn(u, dv.y));
    o.z = __fadd_rn(xv.z, __fmul_rn(u, dv.z));
    o.w = __fadd_rn(xv.w, __fmul_rn(u, dv.w));
    *(float4*)&orow[q * 4] = o;
  }
}

// ---------------- launcher ---------------------------------------------------
extern "C" void kernel_launch(void* const* d_in, const int* in_sizes, int n_in,
                              void* d_out, int out_size, void* d_ws, size_t ws_size,
                              hipStream_t stream) {
  (void)in_sizes; (void)n_in; (void)d_ws; (void)ws_size; (void)out_size;
  const float* x = (const float*)d_in[0];
  const float* W = (const float*)d_in[1];
  float* out = (float*)d_out;

  const uint32_t R0 = 0u, R1 = 42u;  // jax.random.key(42)
  uint32_t ky0, ky1, kd0, kd1, ku0, ku1, ksh0, ksh1;
  tf2x32(R0, R1, 0u, 0u, &ky0, &ky1);
  tf2x32(R0, R1, 0u, 1u, &kd0, &kd1);
  tf2x32(R0, R1, 0u, 2u, &ku0, &ku1);
  tf2x32(R0, R1, 0u, 3u, &ksh0, &ksh1);

  KeyArgs ka;
  ka.ky0 = ky0; ka.ky1 = ky1; ka.ku0 = ku0; ka.ku1 = ku1;
  ka.kd0 = kd0; ka.kd1 = kd1;
  for (uint32_t t = 0; t < 24; ++t) {
    uint32_t a, b;
    tf2x32(ksh0, ksh1, 0u, t, &a, &b);
    ka.ks[2 * t] = a; ka.ks[2 * t + 1] = b;
  }

  slice_fused_kernel<<<dim3(NB / 64), dim3(1024), 0, stream>>>(x, W, out, ka);
}